// Round 1
// baseline (294.360 us; speedup 1.0000x reference)
//
#include <hip/hip_runtime.h>
#include <hip/hip_bf16.h>

typedef _Float16 half8 __attribute__((ext_vector_type(8)));
typedef _Float16 half4v __attribute__((ext_vector_type(4)));
typedef float floatx4 __attribute__((ext_vector_type(4)));

// 100^(i/8), i=0..7, correctly rounded (matches numpy's powf within 1 ulp)
__device__ const float FREQS[8] = {
    1.0f, 1.7782794100389228f, 3.1622776601683795f, 5.623413251903491f,
    10.0f, 17.78279410038923f, 31.622776601683793f, 56.23413251903491f};

// ---------------- kernel 0: weight transpose+convert to f16 [n][k] ----------------
__global__ __launch_bounds__(256) void prep_weights(
    const float* __restrict__ W1, const float* __restrict__ W2,
    const float* __restrict__ W3, _Float16* __restrict__ W1t,
    _Float16* __restrict__ W2t, _Float16* __restrict__ W3t) {
  int tid = blockIdx.x * blockDim.x + threadIdx.x;
  int stride = gridDim.x * blockDim.x;
  for (int i = tid; i < 128 * 32; i += stride) {
    int n = i >> 5, k = i & 31;
    W1t[i] = (_Float16)W1[k * 128 + n];
  }
  for (int i = tid; i < 256 * 128; i += stride) {
    int n = i >> 7, k = i & 127;
    W2t[i] = (_Float16)W2[k * 256 + n];
  }
  for (int i = tid; i < 512 * 256; i += stride) {
    int n = i >> 8, k = i & 255;
    W3t[i] = (_Float16)W3[k * 512 + n];
  }
}

// ---------------- kernel 1: feats + L1 + L2 + LDS scatter of h2 ----------------
// grid: 512 blocks = (bv[6] | tsel[1] | colhalf[1] | pgroup[1]), 256 threads.
// Each block: 512 points, accumulates sum of h2 (its 128-col half) per cell.
#define FS 48    // feats LDS stride (f16), 16B-aligned rows, spreads banks
#define HS 136   // h1 LDS stride (f16)
#define GS 130   // grid accum LDS stride (f32): quad rows land 8 banks apart

__global__ __launch_bounds__(256) void embed_scatter(
    const float* __restrict__ dstart, const float* __restrict__ dend,
    const float* __restrict__ b1, const float* __restrict__ b2,
    const _Float16* __restrict__ W1t, const _Float16* __restrict__ W2t,
    _Float16* __restrict__ grid_part, int* __restrict__ counts_part) {
  __shared__ _Float16 feats[64 * FS];
  __shared__ _Float16 h1s[64 * HS];
  __shared__ float gacc[64 * GS];
  __shared__ float px[64][2];
  __shared__ int cell_s[64];
  __shared__ int hist[64];

  int bid = blockIdx.x;
  int bv = bid >> 3;
  int tsel = (bid >> 2) & 1;
  int ch = (bid >> 1) & 1;  // which 128-col half of h2
  int pg = bid & 1;         // which 512-point half
  const float* src = tsel ? dend : dstart;

  int tid = threadIdx.x;
  int lane = tid & 63;
  int w = tid >> 6;   // wave 0..3
  int ln = lane & 15; // MFMA col / A-row
  int q = lane >> 4;  // MFMA quad

  for (int i = tid; i < 64 * GS; i += 256) gacc[i] = 0.f;
  if (tid < 64) hist[tid] = 0;

  // --- preload weight fragments into VGPRs (loop-invariant) ---
  // layer1: wave w computes h1 cols [w*32, w*32+32)
  half8 w1f[2];
  float b1v[2];
  for (int nt = 0; nt < 2; nt++) {
    int n = w * 32 + nt * 16 + ln;
    w1f[nt] = *(const half8*)&W1t[n * 32 + q * 8];
    b1v[nt] = b1[n];
  }
  // layer2: wave handles mtiles {mset*2, mset*2+1} x 64 cols (nset)
  int mset = w >> 1;
  int nset = w & 1;
  half8 w2f[4][4];
  float b2v[4];
  for (int nt = 0; nt < 4; nt++) {
    int n = ch * 128 + nset * 64 + nt * 16 + ln;
    b2v[nt] = b2[n];
    for (int ks = 0; ks < 4; ks++)
      w2f[nt][ks] = *(const half8*)&W2t[n * 128 + ks * 32 + q * 8];
  }
  __syncthreads();

  for (int g = 0; g < 8; g++) {
    // phase 0: load 64 points, compute cells
    if (tid < 64) {
      int p = bv * 1024 + pg * 512 + g * 64 + tid;
      float x0 = src[p * 2], x1 = src[p * 2 + 1];
      px[tid][0] = x0;
      px[tid][1] = x1;
      int cell = ((int)x0 / 64) * 8 + ((int)x1 / 64);
      cell_s[tid] = cell;
      if (ch == 0) atomicAdd(&hist[cell], 1);
    }
    __syncthreads();
    // phase 1: Fourier feats -> LDS (order per freq: sin x0, sin x1, cos x0, cos x1)
    for (int i = 0; i < 2; i++) {
      int task = tid + i * 256;
      int pt = task >> 3, f = task & 7;
      float fr = FREQS[f];
      float s0, c0, s1, c1;
      sincosf(px[pt][0] * fr, &s0, &c0);
      sincosf(px[pt][1] * fr, &s1, &c1);
      half4v v = {(_Float16)s0, (_Float16)s1, (_Float16)c0, (_Float16)c1};
      *(half4v*)&feats[pt * FS + f * 4] = v;
    }
    __syncthreads();
    // phase 2: layer1 (K=32, one MFMA) + silu -> h1 LDS (f16)
    for (int mt = 0; mt < 4; mt++) {
      half8 af = *(const half8*)&feats[(mt * 16 + ln) * FS + q * 8];
      for (int nt = 0; nt < 2; nt++) {
        floatx4 c = {b1v[nt], b1v[nt], b1v[nt], b1v[nt]};
        c = __builtin_amdgcn_mfma_f32_16x16x32_f16(af, w1f[nt], c, 0, 0, 0);
        int col = w * 32 + nt * 16 + ln;
        for (int r = 0; r < 4; r++) {
          float x = c[r];
          float hv = x / (1.f + __expf(-x));
          h1s[(mt * 16 + q * 4 + r) * HS + col] = (_Float16)hv;
        }
      }
    }
    __syncthreads();
    // phase 3: layer2 (K=128) + silu + LDS scatter into cell accumulator
    for (int mi = 0; mi < 2; mi++) {
      int mt = mset * 2 + mi;
      half8 af[4];
      for (int ks = 0; ks < 4; ks++)
        af[ks] = *(const half8*)&h1s[(mt * 16 + ln) * HS + ks * 32 + q * 8];
      for (int nt = 0; nt < 4; nt++) {
        floatx4 c = {b2v[nt], b2v[nt], b2v[nt], b2v[nt]};
        for (int ks = 0; ks < 4; ks++)
          c = __builtin_amdgcn_mfma_f32_16x16x32_f16(af[ks], w2f[nt][ks], c, 0, 0, 0);
        int col = nset * 64 + nt * 16 + ln;
        for (int r = 0; r < 4; r++) {
          float x = c[r];
          float hv = x / (1.f + __expf(-x));
          int cell = cell_s[mt * 16 + q * 4 + r];
          atomicAdd(&gacc[cell * GS + col], hv);
        }
      }
    }
    __syncthreads();
  }

  // write partial grid (f16) + counts
  int rowbase = (bv * 2 + tsel) * 64;
  {
    int row = tid >> 2;
    int cseg = (tid & 3) * 32;
    for (int j = 0; j < 32; j += 8) {
      half8 v;
      for (int e = 0; e < 8; e++) v[e] = (_Float16)gacc[row * GS + cseg + j + e];
      *(half8*)&grid_part[((size_t)pg * 8192 + rowbase + row) * 256 + ch * 128 + cseg + j] = v;
    }
  }
  if (ch == 0 && tid < 64) counts_part[pg * 8192 + rowbase + tid] = hist[tid];
}

// ---------------- kernel 2: C[8192,512] = (P0+P1)[8192,256] @ W3 + count*b3 ----------------
#define AS 264  // A tile LDS stride (f16)
__global__ __launch_bounds__(256) void layer3(
    const _Float16* __restrict__ grid_part, const int* __restrict__ counts_part,
    const _Float16* __restrict__ W3t, const float* __restrict__ b3,
    float* __restrict__ out) {
  __shared__ _Float16 a_lds[64 * AS];
  int mb = blockIdx.x;  // 128 blocks of 64 rows
  int nb = blockIdx.y;  // 8 blocks of 64 cols
  int tid = threadIdx.x;
  int lane = tid & 63;
  int w = tid >> 6;
  int ln = lane & 15;
  int q = lane >> 4;

  // load A tile (sum of 2 point-half partials)
  {
    int row = tid >> 2;
    int cseg = (tid & 3) * 64;
    const _Float16* p0 = &grid_part[((size_t)(mb * 64 + row)) * 256 + cseg];
    const _Float16* p1 = p0 + (size_t)8192 * 256;
    for (int j = 0; j < 64; j += 8) {
      half8 v0 = *(const half8*)&p0[j];
      half8 v1 = *(const half8*)&p1[j];
      *(half8*)&a_lds[row * AS + cseg + j] = v0 + v1;
    }
  }
  // B fragments (wave handles 16 cols)
  half8 bf[8];
  int n = nb * 64 + w * 16 + ln;
  for (int ks = 0; ks < 8; ks++)
    bf[ks] = *(const half8*)&W3t[n * 256 + ks * 32 + q * 8];
  float b3v = b3[n];
  __syncthreads();

  for (int mt = 0; mt < 4; mt++) {
    floatx4 c = {0.f, 0.f, 0.f, 0.f};
    for (int ks = 0; ks < 8; ks++) {
      half8 af = *(const half8*)&a_lds[(mt * 16 + ln) * AS + ks * 32 + q * 8];
      c = __builtin_amdgcn_mfma_f32_16x16x32_f16(af, bf[ks], c, 0, 0, 0);
    }
    for (int r = 0; r < 4; r++) {
      int row = mb * 64 + mt * 16 + q * 4 + r;
      int cnt = counts_part[row] + counts_part[8192 + row];
      int bvv = row >> 7;
      int ts = (row >> 6) & 1;
      int cell = row & 63;
      out[((size_t)(bvv * 1024 + ts * 512 + n)) * 64 + cell] = c[r] + (float)cnt * b3v;
    }
  }
}

extern "C" void kernel_launch(void* const* d_in, const int* in_sizes, int n_in,
                              void* d_out, int out_size, void* d_ws, size_t ws_size,
                              hipStream_t stream) {
  const float* dstart = (const float*)d_in[0];
  const float* dend = (const float*)d_in[1];
  const float* W1 = (const float*)d_in[2];
  const float* b1 = (const float*)d_in[3];
  const float* W2 = (const float*)d_in[4];
  const float* b2 = (const float*)d_in[5];
  const float* W3 = (const float*)d_in[6];
  const float* b3 = (const float*)d_in[7];
  float* out = (float*)d_out;

  char* ws = (char*)d_ws;
  _Float16* W1t = (_Float16*)(ws);                              // 8 KB
  _Float16* W2t = (_Float16*)(ws + 8192);                       // 64 KB
  _Float16* W3t = (_Float16*)(ws + 8192 + 65536);               // 256 KB
  _Float16* grid_part = (_Float16*)(ws + 8192 + 65536 + 262144);      // 8 MB
  int* counts_part = (int*)(ws + 8192 + 65536 + 262144 + 8388608);    // 64 KB

  hipLaunchKernelGGL(prep_weights, dim3(64), dim3(256), 0, stream,
                     W1, W2, W3, W1t, W2t, W3t);
  hipLaunchKernelGGL(embed_scatter, dim3(512), dim3(256), 0, stream,
                     dstart, dend, b1, b2, W1t, W2t, grid_part, counts_part);
  hipLaunchKernelGGL(layer3, dim3(128, 8), dim3(256), 0, stream,
                     grid_part, counts_part, W3t, b3, out);
}

// Round 2
// 137.052 us; speedup vs baseline: 2.1478x; 2.1478x over previous
//
#include <hip/hip_runtime.h>
#include <hip/hip_bf16.h>

typedef _Float16 half8 __attribute__((ext_vector_type(8)));
typedef _Float16 half4v __attribute__((ext_vector_type(4)));
typedef float floatx4 __attribute__((ext_vector_type(4)));

// 100^(i/8), i=0..7, correctly rounded
__device__ const float FREQS[8] = {
    1.0f, 1.7782794100389228f, 3.1622776601683795f, 5.623413251903491f,
    10.0f, 17.78279410038923f, 31.622776601683793f, 56.23413251903491f};

// sin/cos of m (radians, |m| up to ~3e4) via 2-term Cody-Waite in revolutions.
// Residual error ~|m|*2^-48: matches libm sinf(m) far below f16 rounding.
__device__ inline void fsincos(float m, float& s, float& c) {
  constexpr double I2PI_D = 0.15915494309189533576888376337251;
  constexpr float HI = (float)I2PI_D;
  constexpr float LO = (float)(I2PI_D - (double)HI);
  float k = rintf(m * HI);
  float f = fmaf(m, HI, -k);   // exact-ish residual in revolutions
  f = fmaf(m, LO, f);
  s = __builtin_amdgcn_sinf(f);  // v_sin_f32: input in revolutions, |f|<=0.51
  c = __builtin_amdgcn_cosf(f);
}

__device__ inline float silu(float x) { return x / (1.f + __expf(-x)); }

// ---------------- kernel 0: weight transpose+convert to f16 [n][k] ----------------
__global__ __launch_bounds__(256) void prep_weights(
    const float* __restrict__ W1, const float* __restrict__ W2,
    const float* __restrict__ W3, _Float16* __restrict__ W1t,
    _Float16* __restrict__ W2t, _Float16* __restrict__ W3t) {
  int tid = blockIdx.x * blockDim.x + threadIdx.x;
  int stride = gridDim.x * blockDim.x;
  for (int i = tid; i < 128 * 32; i += stride) {
    int n = i >> 5, k = i & 31;
    W1t[i] = (_Float16)W1[k * 128 + n];
  }
  for (int i = tid; i < 256 * 128; i += stride) {
    int n = i >> 7, k = i & 127;
    W2t[i] = (_Float16)W2[k * 256 + n];
  }
  for (int i = tid; i < 512 * 256; i += stride) {
    int n = i >> 8, k = i & 255;
    W3t[i] = (_Float16)W3[k * 512 + n];
  }
}

// ---------------- kernel 1: feats + L1 + L2 + one-hot MFMA scatter ----------------
// 512 blocks = (bv[6] | tsel[1] | pg[2]); 256 pts/block; 4 waves.
// Wave w: L1 for pts [16w,16w+16) of each 64-pt chunk (swapped: h1^T = W1^T @ feats^T,
// so pt=ln and the h1 LDS round-trip is packed b64/b128); L2 + scatter for cols
// [64w, 64w+64). Scatter via mfma_16x16x16f16 with one-hot A (cells) — the L2
// C-layout IS the scatter B-layout, no transpose. No LDS atomics anywhere.
#define HS 136  // h1t row stride (f16)
__global__ __launch_bounds__(256, 2) void embed_scatter(
    const float* __restrict__ dstart, const float* __restrict__ dend,
    const float* __restrict__ b1, const float* __restrict__ b2,
    const _Float16* __restrict__ W1t, const _Float16* __restrict__ W2t,
    _Float16* __restrict__ partial, int* __restrict__ counts) {
  __shared__ _Float16 h1t[64 * HS];
  __shared__ unsigned char cellb[64];
  __shared__ int hist[64];

  int bid = blockIdx.x;
  int bv = bid >> 3;
  int tsel = (bid >> 2) & 1;
  int pg = bid & 3;
  const float* src = tsel ? dend : dstart;
  int tid = threadIdx.x;
  int lane = tid & 63;
  int w = tid >> 6;
  int ln = lane & 15;
  int q = lane >> 4;

  if (tid < 64) hist[tid] = 0;

  // loop-invariant weight fragments
  half8 w1f[8];    // A-frag of W1^T: m=16mtW+ln (h1col), k=8q+j (feat)
  floatx4 b1v[8];  // b1[16mtW+4q+r]
  for (int mtW = 0; mtW < 8; mtW++) {
    w1f[mtW] = *(const half8*)&W1t[(mtW * 16 + ln) * 32 + q * 8];
    b1v[mtW] = *(const floatx4*)&b1[mtW * 16 + q * 4];
  }
  half8 w2f[4][4];  // B-frag of W2: n=64w+16nt+ln, k=32ks+8q+j
  float b2v[4];
  for (int nt = 0; nt < 4; nt++) {
    int n = w * 64 + nt * 16 + ln;
    b2v[nt] = b2[n];
    for (int ks = 0; ks < 4; ks++)
      w2f[nt][ks] = *(const half8*)&W2t[n * 128 + ks * 32 + q * 8];
  }
  floatx4 sacc[4][4];  // [mc][nt]: cell=16mc+4q+r, col=64w+16nt+ln
  for (int mc = 0; mc < 4; mc++)
    for (int nt = 0; nt < 4; nt++) sacc[mc][nt] = (floatx4){0.f, 0.f, 0.f, 0.f};

  float fA = FREQS[2 * q], fB = FREQS[2 * q + 1];
  int pbase = bv * 1024 + pg * 256;
  __syncthreads();  // hist init visible before first atomicAdd

  for (int c = 0; c < 4; c++) {
    // load point pt=16w+ln (replicated across quads, L1-cached)
    int pl = c * 64 + w * 16 + ln;
    float2 xy = *(const float2*)&src[(size_t)(pbase + pl) * 2];
    int cell = ((int)xy.x >> 6) * 8 + ((int)xy.y >> 6);
    if (q == 0) {
      cellb[w * 16 + ln] = (unsigned char)cell;
      atomicAdd(&hist[cell], 1);
    }
    // feats B-frag in registers: n=pt=ln, k=8q+j -> freqs 2q,2q+1
    half8 fb;
    {
      float s, cc;
      fsincos(xy.x * fA, s, cc); fb[0] = (_Float16)s; fb[2] = (_Float16)cc;
      fsincos(xy.y * fA, s, cc); fb[1] = (_Float16)s; fb[3] = (_Float16)cc;
      fsincos(xy.x * fB, s, cc); fb[4] = (_Float16)s; fb[6] = (_Float16)cc;
      fsincos(xy.y * fB, s, cc); fb[5] = (_Float16)s; fb[7] = (_Float16)cc;
    }
    // L1 swapped: C1[m=h1col][n=pt]; silu -> packed b64 write (4 h1cols per lane)
    for (int mtW = 0; mtW < 8; mtW++) {
      floatx4 cc = __builtin_amdgcn_mfma_f32_16x16x32_f16(w1f[mtW], fb, b1v[mtW], 0, 0, 0);
      half4v hv;
      for (int r = 0; r < 4; r++) hv[r] = (_Float16)silu(cc[r]);
      *(half4v*)&h1t[(w * 16 + ln) * HS + mtW * 16 + q * 4] = hv;
    }
    __syncthreads();
    // L2 (normal: A=h1 pts, B=W2) + one-hot scatter MFMA
    for (int mt = 0; mt < 4; mt++) {
      half8 af[4];
      for (int ks = 0; ks < 4; ks++)
        af[ks] = *(const half8*)&h1t[(mt * 16 + ln) * HS + ks * 32 + q * 8];
      unsigned cw = *(const unsigned*)&cellb[mt * 16 + q * 4];
      int c0 = cw & 255, c1 = (cw >> 8) & 255, c2i = (cw >> 16) & 255, c3 = cw >> 24;
      half4v ao[4];  // one-hot A: m=16mc+ln (cell), k=4q+j (pt)
      for (int mc = 0; mc < 4; mc++) {
        int m = mc * 16 + ln;
        half4v a;
        a[0] = (c0 == m) ? (_Float16)1.f : (_Float16)0.f;
        a[1] = (c1 == m) ? (_Float16)1.f : (_Float16)0.f;
        a[2] = (c2i == m) ? (_Float16)1.f : (_Float16)0.f;
        a[3] = (c3 == m) ? (_Float16)1.f : (_Float16)0.f;
        ao[mc] = a;
      }
      for (int nt = 0; nt < 4; nt++) {
        floatx4 cc = {b2v[nt], b2v[nt], b2v[nt], b2v[nt]};
        for (int ks = 0; ks < 4; ks++)
          cc = __builtin_amdgcn_mfma_f32_16x16x32_f16(af[ks], w2f[nt][ks], cc, 0, 0, 0);
        half4v hb;  // C-layout == scatter B-layout (k=pt=4q+r, n=col=ln)
        for (int r = 0; r < 4; r++) hb[r] = (_Float16)silu(cc[r]);
        for (int mc = 0; mc < 4; mc++)
          sacc[mc][nt] = __builtin_amdgcn_mfma_f32_16x16x16f16(ao[mc], hb, sacc[mc][nt], 0, 0, 0);
      }
    }
    __syncthreads();
  }
  // write partial [cell 64][col 256] f16 + counts
  for (int mc = 0; mc < 4; mc++)
    for (int nt = 0; nt < 4; nt++)
      for (int r = 0; r < 4; r++) {
        int celly = mc * 16 + q * 4 + r;
        int col = w * 64 + nt * 16 + ln;
        partial[(size_t)bid * 16384 + celly * 256 + col] = (_Float16)sacc[mc][nt][r];
      }
  if (tid < 64) counts[bid * 64 + tid] = hist[tid];
}

// ---------------- kernel 2: out = (Σ_pg partial) @ W3 + count*b3 ----------------
// 256 blocks: 32 grid-rows each, all 512 output channels. Swapped GEMM
// (A=W3^T, B=grid rows) so C columns = grid-rows -> stores are cell-contiguous.
#define AS 264
__global__ __launch_bounds__(256) void layer3(
    const _Float16* __restrict__ partial, const int* __restrict__ counts,
    const _Float16* __restrict__ W3t, const float* __restrict__ b3,
    float* __restrict__ out) {
  __shared__ _Float16 a_lds[32 * AS];
  __shared__ float cnt_s[32];
  int mb = blockIdx.x;
  int bvts = mb >> 1;
  int cellbase = (mb & 1) * 32;
  int tid = threadIdx.x;
  {  // stage 32x256 f16 tile = sum of 4 pg partials
    int row = tid >> 3;
    int cs = (tid & 7) * 32;
    size_t base = (size_t)(bvts * 4) * 16384 + (size_t)(cellbase + row) * 256 + cs;
    for (int j = 0; j < 32; j += 8) {
      half8 v = *(const half8*)&partial[base + j] +
                *(const half8*)&partial[base + 16384 + j] +
                *(const half8*)&partial[base + 32768 + j] +
                *(const half8*)&partial[base + 49152 + j];
      *(half8*)&a_lds[row * AS + cs + j] = v;
    }
  }
  if (tid < 32) {
    int base = bvts * 4 * 64 + cellbase + tid;
    cnt_s[tid] = (float)(counts[base] + counts[base + 64] + counts[base + 128] + counts[base + 192]);
  }
  __syncthreads();
  int lane = tid & 63, w = tid >> 6, ln = lane & 15, q = lane >> 4;
  half8 af[2][8];  // B-frag: n=grid-row 16t+ln, k=32ks+8q+j (col)
  for (int t = 0; t < 2; t++)
    for (int ks = 0; ks < 8; ks++)
      af[t][ks] = *(const half8*)&a_lds[(t * 16 + ln) * AS + ks * 32 + q * 8];
  float cf[2] = {cnt_s[ln], cnt_s[16 + ln]};
  for (int i = 0; i < 8; i++) {
    int n = w * 128 + i * 16;
    half8 wf[8];  // A-frag: m=n+ln (W3 col), k
    for (int ks = 0; ks < 8; ks++)
      wf[ks] = *(const half8*)&W3t[(size_t)(n + ln) * 256 + ks * 32 + q * 8];
    floatx4 b3v = *(const floatx4*)&b3[n + q * 4];
    floatx4 acc0 = {0.f, 0.f, 0.f, 0.f}, acc1 = {0.f, 0.f, 0.f, 0.f};
    for (int ks = 0; ks < 8; ks++) {
      acc0 = __builtin_amdgcn_mfma_f32_16x16x32_f16(wf[ks], af[0][ks], acc0, 0, 0, 0);
      acc1 = __builtin_amdgcn_mfma_f32_16x16x32_f16(wf[ks], af[1][ks], acc1, 0, 0, 0);
    }
    for (int r = 0; r < 4; r++) {
      int nn = n + q * 4 + r;
      out[((size_t)(bvts * 512 + nn)) * 64 + cellbase + ln] = acc0[r] + cf[0] * b3v[r];
      out[((size_t)(bvts * 512 + nn)) * 64 + cellbase + 16 + ln] = acc1[r] + cf[1] * b3v[r];
    }
  }
}

extern "C" void kernel_launch(void* const* d_in, const int* in_sizes, int n_in,
                              void* d_out, int out_size, void* d_ws, size_t ws_size,
                              hipStream_t stream) {
  const float* dstart = (const float*)d_in[0];
  const float* dend = (const float*)d_in[1];
  const float* W1 = (const float*)d_in[2];
  const float* b1 = (const float*)d_in[3];
  const float* W2 = (const float*)d_in[4];
  const float* b2 = (const float*)d_in[5];
  const float* W3 = (const float*)d_in[6];
  const float* b3 = (const float*)d_in[7];
  float* out = (float*)d_out;

  char* ws = (char*)d_ws;
  _Float16* W1t = (_Float16*)(ws);                         // 8 KB
  _Float16* W2t = (_Float16*)(ws + 8192);                  // 64 KB
  _Float16* W3t = (_Float16*)(ws + 73728);                 // 256 KB
  _Float16* partial = (_Float16*)(ws + 335872);            // 512*16384*2 = 16 MB
  int* counts = (int*)(ws + 335872 + 16777216);            // 128 KB

  hipLaunchKernelGGL(prep_weights, dim3(64), dim3(256), 0, stream,
                     W1, W2, W3, W1t, W2t, W3t);
  hipLaunchKernelGGL(embed_scatter, dim3(512), dim3(256), 0, stream,
                     dstart, dend, b1, b2, W1t, W2t, partial, counts);
  hipLaunchKernelGGL(layer3, dim3(256), dim3(256), 0, stream,
                     partial, counts, W3t, b3, out);
}

// Round 3
// 119.071 us; speedup vs baseline: 2.4721x; 1.1510x over previous
//
#include <hip/hip_runtime.h>
#include <hip/hip_bf16.h>

typedef _Float16 half8 __attribute__((ext_vector_type(8)));
typedef _Float16 half4v __attribute__((ext_vector_type(4)));
typedef float floatx4 __attribute__((ext_vector_type(4)));
typedef unsigned int uint2v __attribute__((ext_vector_type(2)));

// 100^(i/8), i=0..7, correctly rounded
__device__ const float FREQS[8] = {
    1.0f, 1.7782794100389228f, 3.1622776601683795f, 5.623413251903491f,
    10.0f, 17.78279410038923f, 31.622776601683793f, 56.23413251903491f};

// sin/cos of m (radians) via 2-term Cody-Waite reduction into revolutions,
// then v_sin_f32/v_cos_f32. Error ~|m|*2^-48, far below f16 rounding.
__device__ inline void fsincos(float m, float& s, float& c) {
  constexpr double I2PI_D = 0.15915494309189533576888376337251;
  constexpr float HI = (float)I2PI_D;
  constexpr float LO = (float)(I2PI_D - (double)HI);
  float k = rintf(m * HI);
  float f = fmaf(m, HI, -k);
  f = fmaf(m, LO, f);
  s = __builtin_amdgcn_sinf(f);
  c = __builtin_amdgcn_cosf(f);
}

// fast silu: v_exp + v_rcp (~1ulp), avoids the precise-division sequence
__device__ inline float fsilu(float x) {
  return x * __builtin_amdgcn_rcpf(1.f + __expf(-x));
}

// ---------------- kernel 0: weight prep ----------------
// W1t/W2t: [n][k] f16. W3f: MFMA-fragment-major so layer3's weight loads are
// coalesced 16B/lane: element (n,k) -> [(n>>4)*8 + k>>5][lane=((k>>3)&3)*16 + (n&15)][k&7]
__global__ __launch_bounds__(256) void prep_weights(
    const float* __restrict__ W1, const float* __restrict__ W2,
    const float* __restrict__ W3, _Float16* __restrict__ W1t,
    _Float16* __restrict__ W2t, _Float16* __restrict__ W3f) {
  int tid = blockIdx.x * blockDim.x + threadIdx.x;
  int stride = gridDim.x * blockDim.x;
  for (int i = tid; i < 128 * 32; i += stride) {
    int n = i >> 5, k = i & 31;
    W1t[i] = (_Float16)W1[k * 128 + n];
  }
  for (int i = tid; i < 256 * 128; i += stride) {
    int n = i >> 7, k = i & 127;
    W2t[i] = (_Float16)W2[k * 256 + n];
  }
  for (int i = tid; i < 512 * 256; i += stride) {  // coalesced read of W3
    int k = i >> 9, n = i & 511;
    int it = n >> 4, ln = n & 15, ks = k >> 5, q = (k >> 3) & 3, j = k & 7;
    W3f[((size_t)(it * 8 + ks) * 64 + q * 16 + ln) * 8 + j] = (_Float16)W3[i];
  }
}

// ---------------- kernel 1: feats + L1 + L2 + one-hot MFMA scatter ----------------
// 512 blocks = (bv[6]|tsel[1]|pg[2]), 512 threads (8 waves), 256 pts as 2x128 chunks.
// Wave w: L1 for its 16 pts/chunk (h1^T via swapped MFMA -> packed LDS), then
// L2 + scatter for 32 cols [32w,32w+32). Scatter via mfma_16x16x16f16 one-hot A;
// L2 C-layout == scatter B-layout (no transpose). Partial sums stored in native
// register layout as coalesced 8B/lane stores (unswizzled in layer3).
#define HS 136
__global__ __launch_bounds__(512, 4) void embed_scatter(
    const float* __restrict__ dstart, const float* __restrict__ dend,
    const float* __restrict__ b1, const float* __restrict__ b2,
    const _Float16* __restrict__ W1t, const _Float16* __restrict__ W2t,
    _Float16* __restrict__ swz, int* __restrict__ counts) {
  __shared__ _Float16 h1t[128 * HS];   // 34.8 KB
  __shared__ _Float16 W1lds[4096];     // 8 KB
  __shared__ float b1lds[128];
  __shared__ unsigned char cellb[128];
  __shared__ int hist[64];

  int bid = blockIdx.x;
  int bv = bid >> 3, tsel = (bid >> 2) & 1, pg = bid & 3;
  const float* src = tsel ? dend : dstart;
  int tid = threadIdx.x;
  int lane = tid & 63, w = tid >> 6, ln = lane & 15, q = lane >> 4;

  *(half8*)&W1lds[tid * 8] = *(const half8*)&W1t[tid * 8];
  if (tid < 128) b1lds[tid] = b1[tid];
  if (tid < 64) hist[tid] = 0;

  half8 w2f[2][4];  // B-frag of W2: n=32w+16nt+ln, k=32ks+8q+j
  float b2v[2];
  for (int nt = 0; nt < 2; nt++) {
    int n = w * 32 + nt * 16 + ln;
    b2v[nt] = b2[n];
    for (int ks = 0; ks < 4; ks++)
      w2f[nt][ks] = *(const half8*)&W2t[n * 128 + ks * 32 + q * 8];
  }
  floatx4 sacc[4][2];  // cell=16mc+4q+r, col=32w+16nt+ln
  for (int mc = 0; mc < 4; mc++)
    for (int nt = 0; nt < 2; nt++) sacc[mc][nt] = (floatx4){0.f, 0.f, 0.f, 0.f};

  float fA = FREQS[2 * q], fB = FREQS[2 * q + 1];
  int pbase = bv * 1024 + pg * 256;
  __syncthreads();

  for (int c = 0; c < 2; c++) {
    int pl = c * 128 + w * 16 + ln;
    float2 xy = *(const float2*)&src[(size_t)(pbase + pl) * 2];
    if (q == 0) {
      int cell = ((int)xy.x >> 6) * 8 + ((int)xy.y >> 6);
      cellb[w * 16 + ln] = (unsigned char)cell;
      atomicAdd(&hist[cell], 1);
    }
    half8 fb;  // feats B-frag: n=pt=ln, k=8q+j -> freqs 2q,2q+1
    {
      float s, cc2;
      fsincos(xy.x * fA, s, cc2); fb[0] = (_Float16)s; fb[2] = (_Float16)cc2;
      fsincos(xy.y * fA, s, cc2); fb[1] = (_Float16)s; fb[3] = (_Float16)cc2;
      fsincos(xy.x * fB, s, cc2); fb[4] = (_Float16)s; fb[6] = (_Float16)cc2;
      fsincos(xy.y * fB, s, cc2); fb[5] = (_Float16)s; fb[7] = (_Float16)cc2;
    }
    // L1 swapped: C[m=h1col][n=pt]; silu -> packed b64 LDS write
    for (int mtW = 0; mtW < 8; mtW++) {
      half8 w1f = *(const half8*)&W1lds[(mtW * 16 + ln) * 32 + q * 8];
      floatx4 c1 = *(const floatx4*)&b1lds[mtW * 16 + q * 4];
      c1 = __builtin_amdgcn_mfma_f32_16x16x32_f16(w1f, fb, c1, 0, 0, 0);
      half4v hv;
      for (int r = 0; r < 4; r++) hv[r] = (_Float16)fsilu(c1[r]);
      *(half4v*)&h1t[(w * 16 + ln) * HS + mtW * 16 + q * 4] = hv;
    }
    __syncthreads();
    // L2 + one-hot scatter
    for (int mt = 0; mt < 8; mt++) {
      half8 af[4];
      for (int ks = 0; ks < 4; ks++)
        af[ks] = *(const half8*)&h1t[(mt * 16 + ln) * HS + ks * 32 + q * 8];
      unsigned cw = *(const unsigned*)&cellb[mt * 16 + q * 4];
      unsigned c0 = cw & 255, c1i = (cw >> 8) & 255, c2i = (cw >> 16) & 255, c3i = cw >> 24;
      half4v ao[4];  // one-hot A: m=16mc+ln (cell), k=4q+j (pt)
      for (int mc = 0; mc < 4; mc++) {
        unsigned m = mc * 16 + ln;
        unsigned d0 = (c0 == m ? 0x3C00u : 0u) | (c1i == m ? 0x3C000000u : 0u);
        unsigned d1 = (c2i == m ? 0x3C00u : 0u) | (c3i == m ? 0x3C000000u : 0u);
        uint2v u = {d0, d1};
        ao[mc] = __builtin_bit_cast(half4v, u);
      }
      for (int nt = 0; nt < 2; nt++) {
        floatx4 cc = {b2v[nt], b2v[nt], b2v[nt], b2v[nt]};
        for (int ks = 0; ks < 4; ks++)
          cc = __builtin_amdgcn_mfma_f32_16x16x32_f16(af[ks], w2f[nt][ks], cc, 0, 0, 0);
        half4v hb;  // C-layout == scatter B-layout (k=pt=4q+r, n=col=ln)
        for (int r = 0; r < 4; r++) hb[r] = (_Float16)fsilu(cc[r]);
        for (int mc = 0; mc < 4; mc++)
          sacc[mc][nt] = __builtin_amdgcn_mfma_f32_16x16x16f16(ao[mc], hb, sacc[mc][nt], 0, 0, 0);
      }
    }
    __syncthreads();
  }
  // coalesced swizzled store: element (bid, mc, wnt=2w+nt, lane) = half4 (r0..r3)
  for (int mc = 0; mc < 4; mc++)
    for (int nt = 0; nt < 2; nt++) {
      half4v hv;
      for (int r = 0; r < 4; r++) hv[r] = (_Float16)sacc[mc][nt][r];
      *(half4v*)&swz[((((size_t)bid * 4 + mc) * 16 + w * 2 + nt) * 64 + lane) * 4] = hv;
    }
  if (tid < 64) counts[bid * 64 + tid] = hist[tid];
}

// ---------------- kernel 2: out = (Σ_pg partial) @ W3 + count*b3 ----------------
// 512 blocks = (bvts[128], cellquarter[4]): 16 cells x 512 cols. Unswizzle 4 pg
// partials into a 16x256 f16 LDS tile; swapped GEMM (A=W3 frags, B=cells) so
// stores are cell-contiguous 64B lines.
#define AS 264
__global__ __launch_bounds__(256) void layer3(
    const _Float16* __restrict__ swz, const int* __restrict__ counts,
    const _Float16* __restrict__ W3f, const float* __restrict__ b3,
    float* __restrict__ out) {
  __shared__ _Float16 a_lds[16 * AS];
  __shared__ float cnt_s[16];
  int bb = blockIdx.x;
  int bvts = bb >> 2, cq = bb & 3;
  int tid = threadIdx.x;
  for (int it = 0; it < 4; it++) {
    int cc = it * 256 + tid;
    int wn = cc >> 6, lane2 = cc & 63, q2 = lane2 >> 4, ln2 = lane2 & 15;
    size_t base = ((size_t)bvts * 16 + cq) * 1024 + cc;
    half4v s = (*(const half4v*)&swz[base * 4] +
                *(const half4v*)&swz[(base + 4096) * 4]) +
               (*(const half4v*)&swz[(base + 8192) * 4] +
                *(const half4v*)&swz[(base + 12288) * 4]);
    int col = wn * 16 + ln2;
    for (int r = 0; r < 4; r++) a_lds[(q2 * 4 + r) * AS + col] = s[r];
  }
  if (tid < 16) {
    int base = bvts * 4 * 64 + cq * 16 + tid;
    cnt_s[tid] = (float)(counts[base] + counts[base + 64] +
                         counts[base + 128] + counts[base + 192]);
  }
  __syncthreads();
  int lane = tid & 63, w = tid >> 6, ln = lane & 15, q = lane >> 4;
  half8 af[8];  // B-frag: n=cell=ln, k=32ks+8q+j (col)
  for (int ks = 0; ks < 8; ks++)
    af[ks] = *(const half8*)&a_lds[ln * AS + ks * 32 + q * 8];
  float cntf = cnt_s[ln];
  for (int ii = 0; ii < 8; ii++) {
    int i = w * 8 + ii;  // 16-col tile of 512
    half8 wf[8];
    for (int ks = 0; ks < 8; ks++)
      wf[ks] = *(const half8*)&W3f[((size_t)(i * 8 + ks) * 64 + lane) * 8];
    floatx4 b3v = *(const floatx4*)&b3[i * 16 + q * 4];
    floatx4 acc = {0.f, 0.f, 0.f, 0.f};
    for (int ks = 0; ks < 8; ks++)
      acc = __builtin_amdgcn_mfma_f32_16x16x32_f16(wf[ks], af[ks], acc, 0, 0, 0);
    for (int r = 0; r < 4; r++)
      out[((size_t)bvts * 512 + i * 16 + q * 4 + r) * 64 + cq * 16 + ln] =
          acc[r] + cntf * b3v[r];
  }
}

extern "C" void kernel_launch(void* const* d_in, const int* in_sizes, int n_in,
                              void* d_out, int out_size, void* d_ws, size_t ws_size,
                              hipStream_t stream) {
  const float* dstart = (const float*)d_in[0];
  const float* dend = (const float*)d_in[1];
  const float* W1 = (const float*)d_in[2];
  const float* b1 = (const float*)d_in[3];
  const float* W2 = (const float*)d_in[4];
  const float* b2 = (const float*)d_in[5];
  const float* W3 = (const float*)d_in[6];
  const float* b3 = (const float*)d_in[7];
  float* out = (float*)d_out;

  char* ws = (char*)d_ws;
  _Float16* W1t = (_Float16*)(ws);                  // 8 KB
  _Float16* W2t = (_Float16*)(ws + 8192);           // 64 KB
  _Float16* W3f = (_Float16*)(ws + 73728);          // 256 KB
  _Float16* swz = (_Float16*)(ws + 335872);         // 512*64*256*2 = 16 MB
  int* counts = (int*)(ws + 335872 + 16777216);     // 128 KB

  hipLaunchKernelGGL(prep_weights, dim3(64), dim3(256), 0, stream,
                     W1, W2, W3, W1t, W2t, W3f);
  hipLaunchKernelGGL(embed_scatter, dim3(512), dim3(512), 0, stream,
                     dstart, dend, b1, b2, W1t, W2t, swz, counts);
  hipLaunchKernelGGL(layer3, dim3(512), dim3(256), 0, stream,
                     swz, counts, W3f, b3, out);
}